// Round 19
// baseline (255.586 us; speedup 1.0000x reference)
//
#include <hip/hip_runtime.h>
#include <stdint.h>

typedef unsigned short u16;
typedef __attribute__((ext_vector_type(4))) unsigned short u16x4;
typedef __attribute__((ext_vector_type(8))) short bfx8;   // 8 bf16 = 4 VGPR (MFMA A/B frag)
typedef __attribute__((ext_vector_type(4))) float fx4;    // 16x16 MFMA C/D frag
typedef __attribute__((ext_vector_type(16))) float fx16;  // 32x32 MFMA C/D frag

// ---------- helpers ----------
static __device__ __forceinline__ u16 f2b(float f) {
  union { float f; uint32_t u; } v; v.f = f;
  uint32_t r = v.u + 0x7fffu + ((v.u >> 16) & 1u);   // RNE
  return (u16)(r >> 16);
}

static __device__ __forceinline__ float b2f(u16 u) {
  union { uint32_t u; float f; } v; v.u = ((uint32_t)u) << 16;
  return v.f;
}

static __device__ __forceinline__ uint32_t cvtpk(float lo, float hi) {
  uint32_t r;
  asm("v_cvt_pk_bf16_f32 %0, %1, %2" : "=v"(r) : "v"(lo), "v"(hi));
  return r;
}

static __device__ __forceinline__ float ex2(float x) {   // raw v_exp_f32 (2^x)
  float r;
  asm("v_exp_f32 %0, %1" : "=v"(r) : "v"(x));
  return r;
}

static __device__ __forceinline__ void gload16(const void* g, void* lds) {
  __builtin_amdgcn_global_load_lds((const __attribute__((address_space(1))) uint32_t*)g,
                                   (__attribute__((address_space(3))) uint32_t*)lds,
                                   16, 0, 0);
}

// ---------- f32 -> bf16 convert (8 elems/thread, vectorized) ----------
__global__ __launch_bounds__(256) void f32_to_bf16_k(const float* __restrict__ in,
                                                     u16* __restrict__ out, int n) {
  int i = (blockIdx.x * 256 + threadIdx.x) * 8;
  if (i >= n) return;
  float4 a = *(const float4*)(in + i);
  float4 b = *(const float4*)(in + i + 4);
  bfx8 o;
  o[0]=(short)f2b(a.x); o[1]=(short)f2b(a.y); o[2]=(short)f2b(a.z); o[3]=(short)f2b(a.w);
  o[4]=(short)f2b(b.x); o[5]=(short)f2b(b.y); o[6]=(short)f2b(b.z); o[7]=(short)f2b(b.w);
  *(bfx8*)(out + i) = o;
}

// ---------- 1024x1024 f32 transpose -> bf16 (4 matrices batched in z) ----------
struct TransArgs { const float* in[4]; u16* out[4]; };
__global__ __launch_bounds__(256) void transpose4_k(TransArgs ta) {
  const float* in = ta.in[blockIdx.z];
  u16* out = ta.out[blockIdx.z];
  __shared__ u16 t[64][65];
  const int bx = blockIdx.x * 64, by = blockIdx.y * 64;
  const int tid = threadIdx.x;
#pragma unroll
  for (int i = 0; i < 16; ++i) {
    int idx = tid + i * 256; int r = idx >> 6, c = idx & 63;
    t[c][r] = f2b(in[(size_t)(by + r) * 1024 + bx + c]);
  }
  __syncthreads();
#pragma unroll
  for (int i = 0; i < 16; ++i) {
    int idx = tid + i * 256; int r = idx >> 6, c = idx & 63;
    out[(size_t)(bx + r) * 1024 + by + c] = t[r][c];
  }
}

// ---------- b2[f] = proj_b[f] + sum_e proj_w[f][e]*out_b[e] ----------
__global__ __launch_bounds__(256) void make_b2_k(const float* __restrict__ pw,
                                                 const float* __restrict__ ob,
                                                 const float* __restrict__ pb,
                                                 float* __restrict__ b2) {
  const int f = blockIdx.x, tid = threadIdx.x;
  float s = 0.f;
  for (int e = tid; e < 1024; e += 256) s += pw[(size_t)f * 1024 + e] * ob[e];
#pragma unroll
  for (int d = 1; d < 64; d <<= 1) s += __shfl_xor(s, d);
  __shared__ float red[4];
  if ((tid & 63) == 0) red[tid >> 6] = s;
  __syncthreads();
  if (tid == 0) b2[f] = red[0] + red[1] + red[2] + red[3] + pb[f];
}

// ---------- GEMM core: C = A(MxK) * Bt(NxK)^T, 128x128 tile, BK=64, 4 waves ----------
static __device__ __forceinline__ void gemm_core(const u16* __restrict__ A,
                                                 const u16* __restrict__ Bt,
                                                 int K, int bm, int bn,
                                                 u16* As, u16* Bs, fx4 (&acc)[4][4]) {
  const int tid = threadIdx.x, w = tid >> 6, l = tid & 63, lm = l & 15, lk = l >> 4;
  const int wm = w >> 1, wn = w & 1;
  const int nkt = K >> 6;
  for (int kt = 0; kt < nkt; ++kt) {
#pragma unroll
    for (int i = 0; i < 4; ++i) {
      int off = i * 4096 + w * 1024;         // wave-uniform LDS byte base
      int loff = off + l * 16;               // this lane's byte
      int row = loff >> 7, cb = loff & 127;  // tile row, byte-in-row (BK*2=128B rows)
      gload16((const char*)A + ((size_t)(bm * 128 + row) * K + kt * 64) * 2 + cb,
              (char*)As + off);
      gload16((const char*)Bt + ((size_t)(bn * 128 + row) * K + kt * 64) * 2 + cb,
              (char*)Bs + off);
    }
    __syncthreads();
#pragma unroll
    for (int kk = 0; kk < 2; ++kk) {
      bfx8 a[4], b[4];
#pragma unroll
      for (int mi = 0; mi < 4; ++mi)
        a[mi] = *(const bfx8*)((const char*)As + (wm * 64 + mi * 16 + lm) * 128 + lk * 16 + kk * 64);
#pragma unroll
      for (int nj = 0; nj < 4; ++nj)
        b[nj] = *(const bfx8*)((const char*)Bs + (wn * 64 + nj * 16 + lm) * 128 + lk * 16 + kk * 64);
#pragma unroll
      for (int mi = 0; mi < 4; ++mi)
#pragma unroll
        for (int nj = 0; nj < 4; ++nj)
          acc[mi][nj] = __builtin_amdgcn_mfma_f32_16x16x32_bf16(a[mi], b[nj], acc[mi][nj], 0, 0, 0);
    }
    __syncthreads();
  }
}

// ---------- GEMM core 64: C = A(MxK) * Bt(NxK)^T, 64x128 tile, BK=64, 4 waves (2x2) ----------
static __device__ __forceinline__ void gemm_core64(const u16* __restrict__ A,
                                                   const u16* __restrict__ Bt,
                                                   int K, int bm, int bn,
                                                   u16* As, u16* Bs, fx4 (&acc)[2][4]) {
  const int tid = threadIdx.x, w = tid >> 6, l = tid & 63, lm = l & 15, lk = l >> 4;
  const int wm = w >> 1, wn = w & 1;
  const int nkt = K >> 6;
  for (int kt = 0; kt < nkt; ++kt) {
#pragma unroll
    for (int i = 0; i < 2; ++i) {
      int off = i * 4096 + tid * 16;
      int row = off >> 7, cb = off & 127;
      gload16((const char*)A + ((size_t)(bm * 64 + row) * K + kt * 64) * 2 + cb,
              (char*)As + off);
    }
#pragma unroll
    for (int i = 0; i < 4; ++i) {
      int off = i * 4096 + tid * 16;
      int row = off >> 7, cb = off & 127;
      gload16((const char*)Bt + ((size_t)(bn * 128 + row) * K + kt * 64) * 2 + cb,
              (char*)Bs + off);
    }
    __syncthreads();
#pragma unroll
    for (int kk = 0; kk < 2; ++kk) {
      bfx8 a[2], b[4];
#pragma unroll
      for (int mi = 0; mi < 2; ++mi)
        a[mi] = *(const bfx8*)((const char*)As + (wm * 32 + mi * 16 + lm) * 128 + lk * 16 + kk * 64);
#pragma unroll
      for (int nj = 0; nj < 4; ++nj)
        b[nj] = *(const bfx8*)((const char*)Bs + (wn * 64 + nj * 16 + lm) * 128 + lk * 16 + kk * 64);
#pragma unroll
      for (int mi = 0; mi < 2; ++mi)
#pragma unroll
        for (int nj = 0; nj < 4; ++nj)
          acc[mi][nj] = __builtin_amdgcn_mfma_f32_16x16x32_bf16(a[mi], b[nj], acc[mi][nj], 0, 0, 0);
    }
    __syncthreads();
  }
}

// ---------- combine GEMMs (4 batched in z): 64x128 tiles, grid (16,8,4) ----------
struct CombArgs { const u16* A[4]; const u16* Bt[4]; u16* C[4]; };
__global__ __launch_bounds__(256) void gemm_combine_k(CombArgs ca) {
  const int z = blockIdx.z;
  __shared__ u16 As[4096], Bs[8192];
  fx4 acc[2][4];
#pragma unroll
  for (int mi = 0; mi < 2; ++mi)
#pragma unroll
    for (int nj = 0; nj < 4; ++nj) acc[mi][nj] = 0.f;
  gemm_core64(ca.A[z], ca.Bt[z], 1024, blockIdx.x, blockIdx.y, As, Bs, acc);
  const int tid = threadIdx.x, w = tid >> 6, l = tid & 63, lm = l & 15, lk = l >> 4;
  const int wm = w >> 1, wn = w & 1;
  u16* C = ca.C[z];
#pragma unroll
  for (int mi = 0; mi < 2; ++mi)
#pragma unroll
    for (int nj = 0; nj < 4; ++nj)
#pragma unroll
      for (int r = 0; r < 4; ++r) {
        int m = blockIdx.x * 64 + wm * 32 + mi * 16 + lk * 4 + r;
        int n = blockIdx.y * 128 + wn * 64 + nj * 16 + lm;
        C[(size_t)m * 1024 + n] = f2b(acc[mi][nj][r]);
      }
}

// ---------- QKV GEMM: [8192x1024]x[3072x1024]^T + in_b, XCD-chunked grid ----------
// V epilogue packs the 4 r-values per (mi,nj) into one 8B ushort4 store.
__global__ __launch_bounds__(256) void gemm_qkv_k(const u16* __restrict__ xb,
                                                  const u16* __restrict__ Wc,
                                                  const float* __restrict__ bias,
                                                  u16* __restrict__ Qh, u16* __restrict__ Kh,
                                                  u16* __restrict__ Vh) {
  const int bl = blockIdx.x;
  const int xcd = bl & 7, local = bl >> 3;        // local 0..191
  const int bm = xcd * 8 + (local & 7);           // 0..63
  const int bn = local >> 3;                      // 0..23
  __shared__ u16 As[8192], Bs[8192];
  fx4 acc[4][4];
#pragma unroll
  for (int mi = 0; mi < 4; ++mi)
#pragma unroll
    for (int nj = 0; nj < 4; ++nj) acc[mi][nj] = 0.f;
  gemm_core(xb, Wc, 1024, bm, bn, As, Bs, acc);
  const int tid = threadIdx.x, w = tid >> 6, l = tid & 63, lm = l & 15, lk = l >> 4;
  const int wm = w >> 1, wn = w & 1;
  const int t = bn >> 3;                          // tensor select (tile-uniform)
  if (t == 2) {
    // V: packed 8B stores into Vt[d][k] per-64-tile transposed layout
#pragma unroll
    for (int mi = 0; mi < 4; ++mi)
#pragma unroll
      for (int nj = 0; nj < 4; ++nj) {
        int m0 = bm * 128 + wm * 64 + mi * 16 + lk * 4;
        int n = bn * 128 + wn * 64 + nj * 16 + lm;
        float bia = bias[n];
        int f = n & 1023, hh = f >> 6, hd = f & 63, b = m0 >> 11, s0 = m0 & 2047;
        int sl0 = s0 & 63, st = s0 >> 6;
        size_t hb = ((size_t)(b * 16 + hh)) * 131072;
        u16x4 v4;
        v4[0] = f2b(acc[mi][nj][0] + bia);
        v4[1] = f2b(acc[mi][nj][1] + bia);
        v4[2] = f2b(acc[mi][nj][2] + bia);
        v4[3] = f2b(acc[mi][nj][3] + bia);
        *(u16x4*)(Vh + hb + (size_t)st * 4096 +
                  (size_t)(hd * 64 + (sl0 ^ ((hd & 7) << 3)))) = v4;
      }
  } else {
    u16* dst = (t == 0) ? Qh : Kh;
#pragma unroll
    for (int mi = 0; mi < 4; ++mi)
#pragma unroll
      for (int nj = 0; nj < 4; ++nj)
#pragma unroll
        for (int r = 0; r < 4; ++r) {
          int m = bm * 128 + wm * 64 + mi * 16 + lk * 4 + r;
          int n = bn * 128 + wn * 64 + nj * 16 + lm;
          float v = acc[mi][nj][r] + bias[n];
          int f = n & 1023, hh = f >> 6, hd = f & 63, b = m >> 11, s = m & 2047;
          size_t hb = ((size_t)(b * 16 + hh)) * 131072;   // 2048*64
          size_t idx;
          if (t == 1) {
            idx = hb + (size_t)s * 64 + (hd ^ ((s & 7) << 3));
          } else {
            idx = hb + (size_t)s * 64 + hd;
          }
          dst[idx] = f2b(v);
        }
  }
}

// ---------- final GEMM: ctx x W2^T + b2 + residual, f32 out ----------
// residual from bf16 resid16 when workspace allows (halves the residual stream),
// else from f32 x. 64x128 tiles, XCD-chunked: 1024 flat blocks (4/CU).
__global__ __launch_bounds__(256) void gemm_final_k(const u16* __restrict__ ctx,
                                                    const u16* __restrict__ W2,
                                                    const float* __restrict__ b2,
                                                    const float* __restrict__ x,
                                                    const u16* __restrict__ resid16,
                                                    float* __restrict__ out) {
  const int bl = blockIdx.x;
  const int xcd = bl & 7, local = bl >> 3;        // local 0..127
  const int bm = xcd * 16 + (local & 15);         // 0..127
  const int bn = local >> 4;                      // 0..7
  __shared__ u16 As[4096], Bs[8192];
  fx4 acc[2][4];
#pragma unroll
  for (int mi = 0; mi < 2; ++mi)
#pragma unroll
    for (int nj = 0; nj < 4; ++nj) acc[mi][nj] = 0.f;
  gemm_core64(ctx, W2, 1024, bm, bn, As, Bs, acc);
  const int tid = threadIdx.x, w = tid >> 6, l = tid & 63, lm = l & 15, lk = l >> 4;
  const int wm = w >> 1, wn = w & 1;
#pragma unroll
  for (int mi = 0; mi < 2; ++mi)
#pragma unroll
    for (int nj = 0; nj < 4; ++nj)
#pragma unroll
      for (int r = 0; r < 4; ++r) {
        int m = bm * 64 + wm * 32 + mi * 16 + lk * 4 + r;
        int n = bn * 128 + wn * 64 + nj * 16 + lm;
        size_t idx = (size_t)m * 1024 + n;
        float res = resid16 ? b2f(resid16[idx]) : x[idx];
        out[idx] = acc[mi][nj][r] + b2[n] + res;
      }
}

// ---------- fused attention, 32x32-MFMA path (8 waves, 64-key tiles) ----------
// scores = QK^T/8 + tril(1.0), softmax over FULL row (log2 domain), ctx = P*V.
// 8 waves (512 thr), QBLK=256: each wave owns 32 q rows; lane owns q = qb + (l&31),
// key-half h = l>>5. K/V tile (16KB) staged ONCE per block, double-buffered.
// SYNC: plain __syncthreads() (compiler-fenced vmcnt/lgkm drain + barrier).
__global__ __launch_bounds__(512, 4) void attn_k(const u16* __restrict__ Qh,
                                                 const u16* __restrict__ Kh,
                                                 const u16* __restrict__ Vh,
                                                 u16* __restrict__ ctx) {
  // XCD-chunked swizzle: 512 blocks / 8 XCDs = 64 contiguous work items (8 bh) per XCD.
  const int bl = blockIdx.x;
  const int wk = (bl & 7) * 64 + (bl >> 3);
  const int bh = wk >> 3, qt = wk & 7;
  const int tid = threadIdx.x, w = tid >> 6, l = tid & 63;
  const int ql = l & 31, h = l >> 5;
  __shared__ __align__(16) u16 Ks[2][4096];
  __shared__ __align__(16) u16 Vs[2][4096];

  const float SC = 0.18033688011112042f;    // 0.125 * log2(e)
  const float MA = 1.4426950408889634f;     // 1.0  * log2(e)
  const float THR = 11.541560327111708f;    // 8.0  * log2(e)

  const size_t base = (size_t)bh * 131072;
  const int qb = qt * 256 + w * 32;         // wave q-base
  const int q = qb + ql;                    // lane's q row
  bfx8 qf[4];
  {
    const u16* qp = Qh + base + (size_t)q * 64 + 8 * h;
    qf[0] = *(const bfx8*)(qp);
    qf[1] = *(const bfx8*)(qp + 16);
    qf[2] = *(const bfx8*)(qp + 32);
    qf[3] = *(const bfx8*)(qp + 48);
  }
  float m_run = -1024.f, l_part = 0.f;
  fx16 accO[2];
  accO[0] = 0.f; accO[1] = 0.f;

  const char* Kg = (const char*)(Kh + base);
  const char* Vg = (const char*)(Vh + base);
  const int o = tid * 16;                   // 512 thr x 16B = full 8KB tile per instr
  const int sw8 = (ql & 7) << 4;

#define STAGE(t, s)                                            \
  {                                                            \
    gload16(Kg + (size_t)(t) * 8192 + o, (char*)Ks[s] + o);    \
    gload16(Vg + (size_t)(t) * 8192 + o, (char*)Vs[s] + o);    \
  }

  STAGE(0, 0);
  __syncthreads();

  int cur = 0;
  for (int kt = 0; kt < 32; ++kt) {
    if (kt + 1 < 32) STAGE(kt + 1, cur ^ 1);   // issue early; drained by end-of-iter sync
    __builtin_amdgcn_sched_barrier(0);

    const char* Kc = (const char*)Ks[cur];
    const char* Vc = (const char*)Vs[cur];

    // QK^T (swapped): S[q][key]; lane col = ql, key rows = kb*32 + (r&3)+8*(r>>2)+4h
    fx16 sS[2];
    sS[0] = 0.f; sS[1] = 0.f;
    __builtin_amdgcn_s_setprio(1);
#pragma unroll
    for (int ks = 0; ks < 4; ++ks) {
      bfx8 kf0 = *(const bfx8*)(Kc + (0 * 32 + ql) * 128 + (((ks << 5) | (h << 4)) ^ sw8));
      bfx8 kf1 = *(const bfx8*)(Kc + (1 * 32 + ql) * 128 + (((ks << 5) | (h << 4)) ^ sw8));
      sS[0] = __builtin_amdgcn_mfma_f32_32x32x16_bf16(kf0, qf[ks], sS[0], 0, 0, 0);
      sS[1] = __builtin_amdgcn_mfma_f32_32x32x16_bf16(kf1, qf[ks], sS[1], 0, 0, 0);
    }
    __builtin_amdgcn_s_setprio(0);

    // scale to log2 domain + additive tril mask, bias-folded (cO = -m_run)
    const int dk = kt - (qb >> 6);
    {
      float cO = -m_run, cI = cO + MA;
      if (dk < 0) {
#pragma unroll
        for (int r = 0; r < 16; ++r) {
          sS[0][r] = fmaf(sS[0][r], SC, cI);
          sS[1][r] = fmaf(sS[1][r], SC, cI);
        }
      } else if (dk > 0) {
#pragma unroll
        for (int r = 0; r < 16; ++r) {
          sS[0][r] = fmaf(sS[0][r], SC, cO);
          sS[1][r] = fmaf(sS[1][r], SC, cO);
        }
      } else {
#pragma unroll
        for (int kb = 0; kb < 2; ++kb)
#pragma unroll
          for (int r = 0; r < 16; ++r) {
            int key = kt * 64 + kb * 32 + (r & 3) + 8 * (r >> 2) + 4 * h;
            sS[kb][r] = fmaf(sS[kb][r], SC, (key <= q) ? cI : cO);
          }
      }
    }
    // local max over this lane's 32 scores; row-combine with the partner half lane
    float mx;
    {
      float m0 = fmaxf(fmaxf(sS[0][0], sS[0][1]), fmaxf(sS[0][2], sS[0][3]));
      float m1 = fmaxf(fmaxf(sS[0][4], sS[0][5]), fmaxf(sS[0][6], sS[0][7]));
      float m2 = fmaxf(fmaxf(sS[0][8], sS[0][9]), fmaxf(sS[0][10], sS[0][11]));
      float m3 = fmaxf(fmaxf(sS[0][12], sS[0][13]), fmaxf(sS[0][14], sS[0][15]));
      float m4 = fmaxf(fmaxf(sS[1][0], sS[1][1]), fmaxf(sS[1][2], sS[1][3]));
      float m5 = fmaxf(fmaxf(sS[1][4], sS[1][5]), fmaxf(sS[1][6], sS[1][7]));
      float m6 = fmaxf(fmaxf(sS[1][8], sS[1][9]), fmaxf(sS[1][10], sS[1][11]));
      float m7 = fmaxf(fmaxf(sS[1][12], sS[1][13]), fmaxf(sS[1][14], sS[1][15]));
      mx = fmaxf(fmaxf(fmaxf(m0, m1), fmaxf(m2, m3)), fmaxf(fmaxf(m4, m5), fmaxf(m6, m7)));
    }
    float full = fmaxf(mx, __shfl_xor(mx, 32));   // row max over this tile's 64 keys
    if (!__all(full <= THR)) {                    // rare rescale (defer-max)
      float d = fmaxf(full, 0.f);
      float corr = ex2(-d);
      m_run += d;
      l_part *= corr;
#pragma unroll
      for (int r = 0; r < 16; ++r) {
        int rq = (r & 3) + 8 * (r >> 2) + 4 * h;
        float cr = __shfl(corr, (l & 32) | rq);
        accO[0][r] *= cr;
        accO[1][r] *= cr;
        sS[0][r] -= d;
        sS[1][r] -= d;
      }
    }
    // exp + partial row-sum (this half only; pair-reduced in epilogue)
    fx16 tt;
#pragma unroll
    for (int r = 0; r < 16; ++r) {
      sS[0][r] = ex2(sS[0][r]);
      sS[1][r] = ex2(sS[1][r]);
      tt[r] = sS[0][r] + sS[1][r];
    }
    {
      float ls0 = tt[0] + tt[8],  ls1 = tt[1] + tt[9];
      float ls2 = tt[2] + tt[10], ls3 = tt[3] + tt[11];
      float ls4 = tt[4] + tt[12], ls5 = tt[5] + tt[13];
      float ls6 = tt[6] + tt[14], ls7 = tt[7] + tt[15];
      l_part += ((ls0 + ls4) + (ls1 + ls5)) + ((ls2 + ls6) + (ls3 + ls7));
    }
    // P -> PV A-frags: cvt_pk pairs, then xor-32 exchange (round-8 verified).
    uint32_t pw[8][2];
#pragma unroll
    for (int kb = 0; kb < 2; ++kb)
#pragma unroll
      for (int gg = 0; gg < 4; ++gg) {
        pw[kb * 4 + gg][0] = cvtpk(sS[kb][4 * gg + 0], sS[kb][4 * gg + 1]);
        pw[kb * 4 + gg][1] = cvtpk(sS[kb][4 * gg + 2], sS[kb][4 * gg + 3]);
      }

    // PV: O[q][d] += P[q][k] V[k][d]; B-frag from transposed V tile (plain b128)
    __builtin_amdgcn_s_setprio(1);
#pragma unroll
    for (int ks = 0; ks < 4; ++ks) {
      union { uint32_t u[4]; bfx8 v; } pa;
#pragma unroll
      for (int p = 0; p < 2; ++p) {
        uint32_t contrib = h ? pw[2 * ks][p] : pw[2 * ks + 1][p];
        uint32_t rcv = __shfl_xor(contrib, 32);
        pa.u[p]     = h ? rcv : pw[2 * ks][p];       // keys 16ks+8h+{0..3}
        pa.u[2 + p] = h ? pw[2 * ks + 1][p] : rcv;   // keys 16ks+8h+{4..7}
      }
      bfx8 vf0 = *(const bfx8*)(Vc + (0 * 32 + ql) * 128 + (((ks << 5) | (h << 4)) ^ sw8));
      bfx8 vf1 = *(const bfx8*)(Vc + (1 * 32 + ql) * 128 + (((ks << 5) | (h << 4)) ^ sw8));
      accO[0] = __builtin_amdgcn_mfma_f32_32x32x16_bf16(pa.v, vf0, accO[0], 0, 0, 0);
      accO[1] = __builtin_amdgcn_mfma_f32_32x32x16_bf16(pa.v, vf1, accO[1], 0, 0, 0);
    }
    __builtin_amdgcn_s_setprio(0);

    __syncthreads();   // drains vmcnt (next tile landed) + lgkm, full fence + barrier
    cur ^= 1;
  }
#undef STAGE

  // epilogue: pair-reduce l, write ctx (B,S,D) bf16
  float inv = 1.0f / (l_part + __shfl_xor(l_part, 32));   // full row sum for q
  const int b = bh >> 4, hcol = bh & 15;
#pragma unroll
  for (int r = 0; r < 16; ++r) {
    int rq = (r & 3) + 8 * (r >> 2) + 4 * h;
    float invq = __shfl(inv, (l & 32) | rq);
    size_t rowb = ((size_t)b * 2048 + (qb + rq)) * 1024 + hcol * 64 + ql;
    ctx[rowb]      = f2b(accO[0][r] * invq);   // d = ql
    ctx[rowb + 32] = f2b(accO[1][r] * invq);   // d = 32 + ql
  }
}

// ---------- launch ----------
extern "C" void kernel_launch(void* const* d_in, const int* in_sizes, int n_in,
                              void* d_out, int out_size, void* d_ws, size_t ws_size,
                              hipStream_t stream) {
  (void)in_sizes; (void)n_in; (void)out_size;
  const float* x      = (const float*)d_in[0];
  const float* Wq     = (const float*)d_in[1];
  const float* Wk     = (const float*)d_in[2];
  const float* Wv     = (const float*)d_in[3];
  const float* in_w   = (const float*)d_in[4];
  const float* in_b   = (const float*)d_in[5];
  const float* out_w  = (const float*)d_in[6];
  const float* out_b  = (const float*)d_in[7];
  const float* proj_w = (const float*)d_in[8];
  const float* proj_b = (const float*)d_in[9];
  float* out = (float*)d_out;

  char* ws = (char*)d_ws;
  const size_t MB = 1ull << 20;
  // base layout (72 MB + 4 KB):
  u16* xb   = (u16*)(ws);                    // 16MB bf16(x)
  u16* Qh   = (u16*)(ws + 16 * MB);          // 16MB
  u16* Kh   = (u16*)(ws + 32 * MB);          // 16MB; first 6MB doubles as in_w bf16 (prep only)
  u16* Vh   = (u16*)(ws + 48 * MB);          // 16MB; first 8MB = tmpT, +2MB = proj_w bf16 (prep)
  u16* inwb = Kh;
  u16* tmpT = Vh;
  u16* pwb  = (u16*)(ws + 48 * MB + 8 * MB);
  u16* Wc   = (u16*)(ws + 64 * MB);          // 6MB combined QKV weights
  u16* W2   = (u16*)(ws + 70 * MB);          // 2MB combined output weights
  float* b2 = (float*)(ws + 72 * MB);        // 4KB combined output bias
  // workspace-gated bf16 residual (round-14 proved ws_size >= 124MB on this harness;
  // still gated for safety): keep xb alive, ctx gets its own region.
  const bool bigws = ws_size >= 90 * MB;
  u16* ctx = bigws ? (u16*)(ws + 73 * MB) : xb;
  const u16* resid16 = bigws ? xb : nullptr;

  f32_to_bf16_k<<<4096, 256, 0, stream>>>(x, xb, 8388608);
  f32_to_bf16_k<<<1536, 256, 0, stream>>>(in_w, inwb, 3145728);
  f32_to_bf16_k<<<512, 256, 0, stream>>>(proj_w, pwb, 1048576);

  TransArgs ta;
  ta.in[0] = Wq; ta.in[1] = Wk; ta.in[2] = Wv; ta.in[3] = out_w;
  for (int z = 0; z < 4; ++z) ta.out[z] = tmpT + (size_t)z * 1048576;
  transpose4_k<<<dim3(16, 16, 4), 256, 0, stream>>>(ta);

  CombArgs ca;
  ca.A[0] = inwb; ca.A[1] = inwb + 1048576; ca.A[2] = inwb + 2097152; ca.A[3] = pwb;
  for (int z = 0; z < 4; ++z) ca.Bt[z] = tmpT + (size_t)z * 1048576;
  ca.C[0] = Wc; ca.C[1] = Wc + 1048576; ca.C[2] = Wc + 2097152; ca.C[3] = W2;
  gemm_combine_k<<<dim3(16, 8, 4), 256, 0, stream>>>(ca);

  make_b2_k<<<1024, 256, 0, stream>>>(proj_w, out_b, proj_b, b2);

  gemm_qkv_k<<<1536, 256, 0, stream>>>(xb, Wc, in_b, Qh, Kh, Vh);
  attn_k<<<512, 512, 0, stream>>>(Qh, Kh, Vh, ctx);
  gemm_final_k<<<1024, 256, 0, stream>>>(ctx, W2, b2, x, resid16, out);
}

// Round 20
// 251.681 us; speedup vs baseline: 1.0155x; 1.0155x over previous
//
#include <hip/hip_runtime.h>
#include <stdint.h>

typedef unsigned short u16;
typedef __attribute__((ext_vector_type(4))) unsigned short u16x4;
typedef __attribute__((ext_vector_type(8))) short bfx8;   // 8 bf16 = 4 VGPR (MFMA A/B frag)
typedef __attribute__((ext_vector_type(4))) float fx4;    // 16x16 MFMA C/D frag
typedef __attribute__((ext_vector_type(16))) float fx16;  // 32x32 MFMA C/D frag

// ---------- helpers ----------
static __device__ __forceinline__ u16 f2b(float f) {
  union { float f; uint32_t u; } v; v.f = f;
  uint32_t r = v.u + 0x7fffu + ((v.u >> 16) & 1u);   // RNE
  return (u16)(r >> 16);
}

static __device__ __forceinline__ uint32_t cvtpk(float lo, float hi) {
  uint32_t r;
  asm("v_cvt_pk_bf16_f32 %0, %1, %2" : "=v"(r) : "v"(lo), "v"(hi));
  return r;
}

static __device__ __forceinline__ float ex2(float x) {   // raw v_exp_f32 (2^x)
  float r;
  asm("v_exp_f32 %0, %1" : "=v"(r) : "v"(x));
  return r;
}

static __device__ __forceinline__ void gload16(const void* g, void* lds) {
  __builtin_amdgcn_global_load_lds((const __attribute__((address_space(1))) uint32_t*)g,
                                   (__attribute__((address_space(3))) uint32_t*)lds,
                                   16, 0, 0);
}

// ---------- f32 -> bf16 convert (8 elems/thread, vectorized) ----------
__global__ __launch_bounds__(256) void f32_to_bf16_k(const float* __restrict__ in,
                                                     u16* __restrict__ out, int n) {
  int i = (blockIdx.x * 256 + threadIdx.x) * 8;
  if (i >= n) return;
  float4 a = *(const float4*)(in + i);
  float4 b = *(const float4*)(in + i + 4);
  bfx8 o;
  o[0]=(short)f2b(a.x); o[1]=(short)f2b(a.y); o[2]=(short)f2b(a.z); o[3]=(short)f2b(a.w);
  o[4]=(short)f2b(b.x); o[5]=(short)f2b(b.y); o[6]=(short)f2b(b.z); o[7]=(short)f2b(b.w);
  *(bfx8*)(out + i) = o;
}

// ---------- 1024x1024 f32 transpose -> bf16 (4 matrices batched in z) ----------
struct TransArgs { const float* in[4]; u16* out[4]; };
__global__ __launch_bounds__(256) void transpose4_k(TransArgs ta) {
  const float* in = ta.in[blockIdx.z];
  u16* out = ta.out[blockIdx.z];
  __shared__ u16 t[64][65];
  const int bx = blockIdx.x * 64, by = blockIdx.y * 64;
  const int tid = threadIdx.x;
#pragma unroll
  for (int i = 0; i < 16; ++i) {
    int idx = tid + i * 256; int r = idx >> 6, c = idx & 63;
    t[c][r] = f2b(in[(size_t)(by + r) * 1024 + bx + c]);
  }
  __syncthreads();
#pragma unroll
  for (int i = 0; i < 16; ++i) {
    int idx = tid + i * 256; int r = idx >> 6, c = idx & 63;
    out[(size_t)(bx + r) * 1024 + by + c] = t[r][c];
  }
}

// ---------- b2[f] = proj_b[f] + sum_e proj_w[f][e]*out_b[e] ----------
__global__ __launch_bounds__(256) void make_b2_k(const float* __restrict__ pw,
                                                 const float* __restrict__ ob,
                                                 const float* __restrict__ pb,
                                                 float* __restrict__ b2) {
  const int f = blockIdx.x, tid = threadIdx.x;
  float s = 0.f;
  for (int e = tid; e < 1024; e += 256) s += pw[(size_t)f * 1024 + e] * ob[e];
#pragma unroll
  for (int d = 1; d < 64; d <<= 1) s += __shfl_xor(s, d);
  __shared__ float red[4];
  if ((tid & 63) == 0) red[tid >> 6] = s;
  __syncthreads();
  if (tid == 0) b2[f] = red[0] + red[1] + red[2] + red[3] + pb[f];
}

// ---------- GEMM core: C = A(MxK) * Bt(NxK)^T, 128x128 tile, BK=64, 4 waves ----------
static __device__ __forceinline__ void gemm_core(const u16* __restrict__ A,
                                                 const u16* __restrict__ Bt,
                                                 int K, int bm, int bn,
                                                 u16* As, u16* Bs, fx4 (&acc)[4][4]) {
  const int tid = threadIdx.x, w = tid >> 6, l = tid & 63, lm = l & 15, lk = l >> 4;
  const int wm = w >> 1, wn = w & 1;
  const int nkt = K >> 6;
  for (int kt = 0; kt < nkt; ++kt) {
#pragma unroll
    for (int i = 0; i < 4; ++i) {
      int off = i * 4096 + w * 1024;         // wave-uniform LDS byte base
      int loff = off + l * 16;               // this lane's byte
      int row = loff >> 7, cb = loff & 127;  // tile row, byte-in-row (BK*2=128B rows)
      gload16((const char*)A + ((size_t)(bm * 128 + row) * K + kt * 64) * 2 + cb,
              (char*)As + off);
      gload16((const char*)Bt + ((size_t)(bn * 128 + row) * K + kt * 64) * 2 + cb,
              (char*)Bs + off);
    }
    __syncthreads();
#pragma unroll
    for (int kk = 0; kk < 2; ++kk) {
      bfx8 a[4], b[4];
#pragma unroll
      for (int mi = 0; mi < 4; ++mi)
        a[mi] = *(const bfx8*)((const char*)As + (wm * 64 + mi * 16 + lm) * 128 + lk * 16 + kk * 64);
#pragma unroll
      for (int nj = 0; nj < 4; ++nj)
        b[nj] = *(const bfx8*)((const char*)Bs + (wn * 64 + nj * 16 + lm) * 128 + lk * 16 + kk * 64);
#pragma unroll
      for (int mi = 0; mi < 4; ++mi)
#pragma unroll
        for (int nj = 0; nj < 4; ++nj)
          acc[mi][nj] = __builtin_amdgcn_mfma_f32_16x16x32_bf16(a[mi], b[nj], acc[mi][nj], 0, 0, 0);
    }
    __syncthreads();
  }
}

// ---------- GEMM core 64: C = A(MxK) * Bt(NxK)^T, 64x128 tile, BK=64, 4 waves (2x2) ----------
static __device__ __forceinline__ void gemm_core64(const u16* __restrict__ A,
                                                   const u16* __restrict__ Bt,
                                                   int K, int bm, int bn,
                                                   u16* As, u16* Bs, fx4 (&acc)[2][4]) {
  const int tid = threadIdx.x, w = tid >> 6, l = tid & 63, lm = l & 15, lk = l >> 4;
  const int wm = w >> 1, wn = w & 1;
  const int nkt = K >> 6;
  for (int kt = 0; kt < nkt; ++kt) {
#pragma unroll
    for (int i = 0; i < 2; ++i) {
      int off = i * 4096 + tid * 16;
      int row = off >> 7, cb = off & 127;
      gload16((const char*)A + ((size_t)(bm * 64 + row) * K + kt * 64) * 2 + cb,
              (char*)As + off);
    }
#pragma unroll
    for (int i = 0; i < 4; ++i) {
      int off = i * 4096 + tid * 16;
      int row = off >> 7, cb = off & 127;
      gload16((const char*)Bt + ((size_t)(bn * 128 + row) * K + kt * 64) * 2 + cb,
              (char*)Bs + off);
    }
    __syncthreads();
#pragma unroll
    for (int kk = 0; kk < 2; ++kk) {
      bfx8 a[2], b[4];
#pragma unroll
      for (int mi = 0; mi < 2; ++mi)
        a[mi] = *(const bfx8*)((const char*)As + (wm * 32 + mi * 16 + lm) * 128 + lk * 16 + kk * 64);
#pragma unroll
      for (int nj = 0; nj < 4; ++nj)
        b[nj] = *(const bfx8*)((const char*)Bs + (wn * 64 + nj * 16 + lm) * 128 + lk * 16 + kk * 64);
#pragma unroll
      for (int mi = 0; mi < 2; ++mi)
#pragma unroll
        for (int nj = 0; nj < 4; ++nj)
          acc[mi][nj] = __builtin_amdgcn_mfma_f32_16x16x32_bf16(a[mi], b[nj], acc[mi][nj], 0, 0, 0);
    }
    __syncthreads();
  }
}

// ---------- combine GEMMs (4 batched in z): 64x128 tiles, grid (16,8,4) ----------
struct CombArgs { const u16* A[4]; const u16* Bt[4]; u16* C[4]; };
__global__ __launch_bounds__(256) void gemm_combine_k(CombArgs ca) {
  const int z = blockIdx.z;
  __shared__ u16 As[4096], Bs[8192];
  fx4 acc[2][4];
#pragma unroll
  for (int mi = 0; mi < 2; ++mi)
#pragma unroll
    for (int nj = 0; nj < 4; ++nj) acc[mi][nj] = 0.f;
  gemm_core64(ca.A[z], ca.Bt[z], 1024, blockIdx.x, blockIdx.y, As, Bs, acc);
  const int tid = threadIdx.x, w = tid >> 6, l = tid & 63, lm = l & 15, lk = l >> 4;
  const int wm = w >> 1, wn = w & 1;
  u16* C = ca.C[z];
#pragma unroll
  for (int mi = 0; mi < 2; ++mi)
#pragma unroll
    for (int nj = 0; nj < 4; ++nj)
#pragma unroll
      for (int r = 0; r < 4; ++r) {
        int m = blockIdx.x * 64 + wm * 32 + mi * 16 + lk * 4 + r;
        int n = blockIdx.y * 128 + wn * 64 + nj * 16 + lm;
        C[(size_t)m * 1024 + n] = f2b(acc[mi][nj][r]);
      }
}

// ---------- QKV GEMM: [8192x1024]x[3072x1024]^T + in_b, XCD-chunked grid ----------
// V epilogue packs the 4 r-values per (mi,nj) into one 8B ushort4 store:
// s0 = ...+lk*4 is 4-aligned, swizzle c=(hd&7)<<3 touches bits>=3 only, so
// (sl0+r)^c = (sl0^c)+r (consecutive, order-preserved); st/b/hd/bias r-invariant.
__global__ __launch_bounds__(256) void gemm_qkv_k(const u16* __restrict__ xb,
                                                  const u16* __restrict__ Wc,
                                                  const float* __restrict__ bias,
                                                  u16* __restrict__ Qh, u16* __restrict__ Kh,
                                                  u16* __restrict__ Vh) {
  const int bl = blockIdx.x;
  const int xcd = bl & 7, local = bl >> 3;        // local 0..191
  const int bm = xcd * 8 + (local & 7);           // 0..63
  const int bn = local >> 3;                      // 0..23
  __shared__ u16 As[8192], Bs[8192];
  fx4 acc[4][4];
#pragma unroll
  for (int mi = 0; mi < 4; ++mi)
#pragma unroll
    for (int nj = 0; nj < 4; ++nj) acc[mi][nj] = 0.f;
  gemm_core(xb, Wc, 1024, bm, bn, As, Bs, acc);
  const int tid = threadIdx.x, w = tid >> 6, l = tid & 63, lm = l & 15, lk = l >> 4;
  const int wm = w >> 1, wn = w & 1;
  const int t = bn >> 3;                          // tensor select (tile-uniform)
  if (t == 2) {
    // V: packed 8B stores into Vt[d][k] per-64-tile transposed layout
#pragma unroll
    for (int mi = 0; mi < 4; ++mi)
#pragma unroll
      for (int nj = 0; nj < 4; ++nj) {
        int m0 = bm * 128 + wm * 64 + mi * 16 + lk * 4;
        int n = bn * 128 + wn * 64 + nj * 16 + lm;
        float bia = bias[n];
        int f = n & 1023, hh = f >> 6, hd = f & 63, b = m0 >> 11, s0 = m0 & 2047;
        int sl0 = s0 & 63, st = s0 >> 6;
        size_t hb = ((size_t)(b * 16 + hh)) * 131072;
        u16x4 v4;
        v4[0] = f2b(acc[mi][nj][0] + bia);
        v4[1] = f2b(acc[mi][nj][1] + bia);
        v4[2] = f2b(acc[mi][nj][2] + bia);
        v4[3] = f2b(acc[mi][nj][3] + bia);
        *(u16x4*)(Vh + hb + (size_t)st * 4096 +
                  (size_t)(hd * 64 + (sl0 ^ ((hd & 7) << 3)))) = v4;
      }
  } else {
    u16* dst = (t == 0) ? Qh : Kh;
#pragma unroll
    for (int mi = 0; mi < 4; ++mi)
#pragma unroll
      for (int nj = 0; nj < 4; ++nj)
#pragma unroll
        for (int r = 0; r < 4; ++r) {
          int m = bm * 128 + wm * 64 + mi * 16 + lk * 4 + r;
          int n = bn * 128 + wn * 64 + nj * 16 + lm;
          float v = acc[mi][nj][r] + bias[n];
          int f = n & 1023, hh = f >> 6, hd = f & 63, b = m >> 11, s = m & 2047;
          size_t hb = ((size_t)(b * 16 + hh)) * 131072;   // 2048*64
          size_t idx;
          if (t == 1) {
            idx = hb + (size_t)s * 64 + (hd ^ ((s & 7) << 3));
          } else {
            idx = hb + (size_t)s * 64 + hd;
          }
          dst[idx] = f2b(v);
        }
  }
}

// ---------- final GEMM: ctx[8192x1024] x W2[1024x1024]^T + b2 + x, f32 out ----------
// 64x128 tiles, XCD-chunked: 1024 flat blocks (4/CU); XCD j owns bm64 in [16j, 16j+16).
__global__ __launch_bounds__(256) void gemm_final_k(const u16* __restrict__ ctx,
                                                    const u16* __restrict__ W2,
                                                    const float* __restrict__ b2,
                                                    const float* __restrict__ x,
                                                    float* __restrict__ out) {
  const int bl = blockIdx.x;
  const int xcd = bl & 7, local = bl >> 3;        // local 0..127
  const int bm = xcd * 16 + (local & 15);         // 0..127
  const int bn = local >> 4;                      // 0..7
  __shared__ u16 As[4096], Bs[8192];
  fx4 acc[2][4];
#pragma unroll
  for (int mi = 0; mi < 2; ++mi)
#pragma unroll
    for (int nj = 0; nj < 4; ++nj) acc[mi][nj] = 0.f;
  gemm_core64(ctx, W2, 1024, bm, bn, As, Bs, acc);
  const int tid = threadIdx.x, w = tid >> 6, l = tid & 63, lm = l & 15, lk = l >> 4;
  const int wm = w >> 1, wn = w & 1;
#pragma unroll
  for (int mi = 0; mi < 2; ++mi)
#pragma unroll
    for (int nj = 0; nj < 4; ++nj)
#pragma unroll
      for (int r = 0; r < 4; ++r) {
        int m = bm * 64 + wm * 32 + mi * 16 + lk * 4 + r;
        int n = bn * 128 + wn * 64 + nj * 16 + lm;
        size_t idx = (size_t)m * 1024 + n;
        out[idx] = acc[mi][nj][r] + b2[n] + x[idx];
      }
}

// ---------- fused attention, 32x32-MFMA path (8 waves, 64-key tiles) ----------
// scores = QK^T/8 + tril(1.0), softmax over FULL row (log2 domain), ctx = P*V.
// 8 waves (512 thr), QBLK=256: each wave owns 32 q rows; lane owns q = qb + (l&31),
// key-half h = l>>5. K/V tile (16KB) staged ONCE per block, double-buffered.
// SYNC: plain __syncthreads() (compiler-fenced vmcnt/lgkm drain + barrier).
__global__ __launch_bounds__(512, 4) void attn_k(const u16* __restrict__ Qh,
                                                 const u16* __restrict__ Kh,
                                                 const u16* __restrict__ Vh,
                                                 u16* __restrict__ ctx) {
  // XCD-chunked swizzle: 512 blocks / 8 XCDs = 64 contiguous work items (8 bh) per XCD.
  const int bl = blockIdx.x;
  const int wk = (bl & 7) * 64 + (bl >> 3);
  const int bh = wk >> 3, qt = wk & 7;
  const int tid = threadIdx.x, w = tid >> 6, l = tid & 63;
  const int ql = l & 31, h = l >> 5;
  __shared__ __align__(16) u16 Ks[2][4096];
  __shared__ __align__(16) u16 Vs[2][4096];

  const float SC = 0.18033688011112042f;    // 0.125 * log2(e)
  const float MA = 1.4426950408889634f;     // 1.0  * log2(e)
  const float THR = 11.541560327111708f;    // 8.0  * log2(e)

  const size_t base = (size_t)bh * 131072;
  const int qb = qt * 256 + w * 32;         // wave q-base
  const int q = qb + ql;                    // lane's q row
  bfx8 qf[4];
  {
    const u16* qp = Qh + base + (size_t)q * 64 + 8 * h;
    qf[0] = *(const bfx8*)(qp);
    qf[1] = *(const bfx8*)(qp + 16);
    qf[2] = *(const bfx8*)(qp + 32);
    qf[3] = *(const bfx8*)(qp + 48);
  }
  float m_run = -1024.f, l_part = 0.f;
  fx16 accO[2];
  accO[0] = 0.f; accO[1] = 0.f;

  const char* Kg = (const char*)(Kh + base);
  const char* Vg = (const char*)(Vh + base);
  const int o = tid * 16;                   // 512 thr x 16B = full 8KB tile per instr
  const int sw8 = (ql & 7) << 4;

#define STAGE(t, s)                                            \
  {                                                            \
    gload16(Kg + (size_t)(t) * 8192 + o, (char*)Ks[s] + o);    \
    gload16(Vg + (size_t)(t) * 8192 + o, (char*)Vs[s] + o);    \
  }

  STAGE(0, 0);
  __syncthreads();

  int cur = 0;
  for (int kt = 0; kt < 32; ++kt) {
    if (kt + 1 < 32) STAGE(kt + 1, cur ^ 1);   // issue early; drained by end-of-iter sync
    __builtin_amdgcn_sched_barrier(0);

    const char* Kc = (const char*)Ks[cur];
    const char* Vc = (const char*)Vs[cur];

    // QK^T (swapped): S[q][key]; lane col = ql, key rows = kb*32 + (r&3)+8*(r>>2)+4h
    fx16 sS[2];
    sS[0] = 0.f; sS[1] = 0.f;
    __builtin_amdgcn_s_setprio(1);
#pragma unroll
    for (int ks = 0; ks < 4; ++ks) {
      bfx8 kf0 = *(const bfx8*)(Kc + (0 * 32 + ql) * 128 + (((ks << 5) | (h << 4)) ^ sw8));
      bfx8 kf1 = *(const bfx8*)(Kc + (1 * 32 + ql) * 128 + (((ks << 5) | (h << 4)) ^ sw8));
      sS[0] = __builtin_amdgcn_mfma_f32_32x32x16_bf16(kf0, qf[ks], sS[0], 0, 0, 0);
      sS[1] = __builtin_amdgcn_mfma_f32_32x32x16_bf16(kf1, qf[ks], sS[1], 0, 0, 0);
    }
    __builtin_amdgcn_s_setprio(0);

    // scale to log2 domain + additive tril mask, bias-folded (cO = -m_run)
    const int dk = kt - (qb >> 6);
    {
      float cO = -m_run, cI = cO + MA;
      if (dk < 0) {
#pragma unroll
        for (int r = 0; r < 16; ++r) {
          sS[0][r] = fmaf(sS[0][r], SC, cI);
          sS[1][r] = fmaf(sS[1][r], SC, cI);
        }
      } else if (dk > 0) {
#pragma unroll
        for (int r = 0; r < 16; ++r) {
          sS[0][r] = fmaf(sS[0][r], SC, cO);
          sS[1][r] = fmaf(sS[1][r], SC, cO);
        }
      } else {
#pragma unroll
        for (int kb = 0; kb < 2; ++kb)
#pragma unroll
          for (int r = 0; r < 16; ++r) {
            int key = kt * 64 + kb * 32 + (r & 3) + 8 * (r >> 2) + 4 * h;
            sS[kb][r] = fmaf(sS[kb][r], SC, (key <= q) ? cI : cO);
          }
      }
    }
    // local max over this lane's 32 scores; row-combine with the partner half lane
    float mx;
    {
      float m0 = fmaxf(fmaxf(sS[0][0], sS[0][1]), fmaxf(sS[0][2], sS[0][3]));
      float m1 = fmaxf(fmaxf(sS[0][4], sS[0][5]), fmaxf(sS[0][6], sS[0][7]));
      float m2 = fmaxf(fmaxf(sS[0][8], sS[0][9]), fmaxf(sS[0][10], sS[0][11]));
      float m3 = fmaxf(fmaxf(sS[0][12], sS[0][13]), fmaxf(sS[0][14], sS[0][15]));
      float m4 = fmaxf(fmaxf(sS[1][0], sS[1][1]), fmaxf(sS[1][2], sS[1][3]));
      float m5 = fmaxf(fmaxf(sS[1][4], sS[1][5]), fmaxf(sS[1][6], sS[1][7]));
      float m6 = fmaxf(fmaxf(sS[1][8], sS[1][9]), fmaxf(sS[1][10], sS[1][11]));
      float m7 = fmaxf(fmaxf(sS[1][12], sS[1][13]), fmaxf(sS[1][14], sS[1][15]));
      mx = fmaxf(fmaxf(fmaxf(m0, m1), fmaxf(m2, m3)), fmaxf(fmaxf(m4, m5), fmaxf(m6, m7)));
    }
    float full = fmaxf(mx, __shfl_xor(mx, 32));   // row max over this tile's 64 keys
    if (!__all(full <= THR)) {                    // rare rescale (defer-max)
      float d = fmaxf(full, 0.f);
      float corr = ex2(-d);
      m_run += d;
      l_part *= corr;
#pragma unroll
      for (int r = 0; r < 16; ++r) {
        int rq = (r & 3) + 8 * (r >> 2) + 4 * h;
        float cr = __shfl(corr, (l & 32) | rq);
        accO[0][r] *= cr;
        accO[1][r] *= cr;
        sS[0][r] -= d;
        sS[1][r] -= d;
      }
    }
    // exp + partial row-sum (this half only; pair-reduced in epilogue)
    fx16 tt;
#pragma unroll
    for (int r = 0; r < 16; ++r) {
      sS[0][r] = ex2(sS[0][r]);
      sS[1][r] = ex2(sS[1][r]);
      tt[r] = sS[0][r] + sS[1][r];
    }
    {
      float ls0 = tt[0] + tt[8],  ls1 = tt[1] + tt[9];
      float ls2 = tt[2] + tt[10], ls3 = tt[3] + tt[11];
      float ls4 = tt[4] + tt[12], ls5 = tt[5] + tt[13];
      float ls6 = tt[6] + tt[14], ls7 = tt[7] + tt[15];
      l_part += ((ls0 + ls4) + (ls1 + ls5)) + ((ls2 + ls6) + (ls3 + ls7));
    }
    // P -> PV A-frags: cvt_pk pairs, then xor-32 exchange (round-8 verified).
    uint32_t pw[8][2];
#pragma unroll
    for (int kb = 0; kb < 2; ++kb)
#pragma unroll
      for (int gg = 0; gg < 4; ++gg) {
        pw[kb * 4 + gg][0] = cvtpk(sS[kb][4 * gg + 0], sS[kb][4 * gg + 1]);
        pw[kb * 4 + gg][1] = cvtpk(sS[kb][4 * gg + 2], sS[kb][4 * gg + 3]);
      }

    // PV: O[q][d] += P[q][k] V[k][d]; B-frag from transposed V tile (plain b128)
    __builtin_amdgcn_s_setprio(1);
#pragma unroll
    for (int ks = 0; ks < 4; ++ks) {
      union { uint32_t u[4]; bfx8 v; } pa;
#pragma unroll
      for (int p = 0; p < 2; ++p) {
        uint32_t contrib = h ? pw[2 * ks][p] : pw[2 * ks + 1][p];
        uint32_t rcv = __shfl_xor(contrib, 32);
        pa.u[p]     = h ? rcv : pw[2 * ks][p];       // keys 16ks+8h+{0..3}
        pa.u[2 + p] = h ? pw[2 * ks + 1][p] : rcv;   // keys 16ks+8h+{4..7}
      }
      bfx8 vf0 = *(const bfx8*)(Vc + (0 * 32 + ql) * 128 + (((ks << 5) | (h << 4)) ^ sw8));
      bfx8 vf1 = *(const bfx8*)(Vc + (1 * 32 + ql) * 128 + (((ks << 5) | (h << 4)) ^ sw8));
      accO[0] = __builtin_amdgcn_mfma_f32_32x32x16_bf16(pa.v, vf0, accO[0], 0, 0, 0);
      accO[1] = __builtin_amdgcn_mfma_f32_32x32x16_bf16(pa.v, vf1, accO[1], 0, 0, 0);
    }
    __builtin_amdgcn_s_setprio(0);

    __syncthreads();   // drains vmcnt (next tile landed) + lgkm, full fence + barrier
    cur ^= 1;
  }
#undef STAGE

  // epilogue: pair-reduce l, write ctx (B,S,D) bf16
  float inv = 1.0f / (l_part + __shfl_xor(l_part, 32));   // full row sum for q
  const int b = bh >> 4, hcol = bh & 15;
#pragma unroll
  for (int r = 0; r < 16; ++r) {
    int rq = (r & 3) + 8 * (r >> 2) + 4 * h;
    float invq = __shfl(inv, (l & 32) | rq);
    size_t rowb = ((size_t)b * 2048 + (qb + rq)) * 1024 + hcol * 64 + ql;
    ctx[rowb]      = f2b(accO[0][r] * invq);   // d = ql
    ctx[rowb + 32] = f2b(accO[1][r] * invq);   // d = 32 + ql
  }
}

// ---------- launch ----------
extern "C" void kernel_launch(void* const* d_in, const int* in_sizes, int n_in,
                              void* d_out, int out_size, void* d_ws, size_t ws_size,
                              hipStream_t stream) {
  (void)in_sizes; (void)n_in; (void)out_size; (void)ws_size;
  const float* x      = (const float*)d_in[0];
  const float* Wq     = (const float*)d_in[1];
  const float* Wk     = (const float*)d_in[2];
  const float* Wv     = (const float*)d_in[3];
  const float* in_w   = (const float*)d_in[4];
  const float* in_b   = (const float*)d_in[5];
  const float* out_w  = (const float*)d_in[6];
  const float* out_b  = (const float*)d_in[7];
  const float* proj_w = (const float*)d_in[8];
  const float* proj_b = (const float*)d_in[9];
  float* out = (float*)d_out;

  char* ws = (char*)d_ws;
  const size_t MB = 1ull << 20;
  // lifetime-overlapped layout (72 MB + 4 KB total):
  u16* xb   = (u16*)(ws);                    // 16MB; dead after QKV GEMM -> reused as ctx
  u16* ctx  = xb;
  u16* Qh   = (u16*)(ws + 16 * MB);          // 16MB
  u16* Kh   = (u16*)(ws + 32 * MB);          // 16MB; first 6MB doubles as in_w bf16 (prep only)
  u16* Vh   = (u16*)(ws + 48 * MB);          // 16MB; first 8MB = tmpT, +2MB = proj_w bf16 (prep only)
  u16* inwb = Kh;
  u16* tmpT = Vh;
  u16* pwb  = (u16*)(ws + 48 * MB + 8 * MB);
  u16* Wc   = (u16*)(ws + 64 * MB);          // 6MB combined QKV weights
  u16* W2   = (u16*)(ws + 70 * MB);          // 2MB combined output weights
  float* b2 = (float*)(ws + 72 * MB);        // 4KB combined output bias

  f32_to_bf16_k<<<4096, 256, 0, stream>>>(x, xb, 8388608);
  f32_to_bf16_k<<<1536, 256, 0, stream>>>(in_w, inwb, 3145728);
  f32_to_bf16_k<<<512, 256, 0, stream>>>(proj_w, pwb, 1048576);

  TransArgs ta;
  ta.in[0] = Wq; ta.in[1] = Wk; ta.in[2] = Wv; ta.in[3] = out_w;
  for (int z = 0; z < 4; ++z) ta.out[z] = tmpT + (size_t)z * 1048576;
  transpose4_k<<<dim3(16, 16, 4), 256, 0, stream>>>(ta);

  CombArgs ca;
  ca.A[0] = inwb; ca.A[1] = inwb + 1048576; ca.A[2] = inwb + 2097152; ca.A[3] = pwb;
  for (int z = 0; z < 4; ++z) ca.Bt[z] = tmpT + (size_t)z * 1048576;
  ca.C[0] = Wc; ca.C[1] = Wc + 1048576; ca.C[2] = Wc + 2097152; ca.C[3] = W2;
  gemm_combine_k<<<dim3(16, 8, 4), 256, 0, stream>>>(ca);

  make_b2_k<<<1024, 256, 0, stream>>>(proj_w, out_b, proj_b, b2);

  gemm_qkv_k<<<1536, 256, 0, stream>>>(xb, Wc, in_b, Qh, Kh, Vh);
  attn_k<<<512, 512, 0, stream>>>(Qh, Kh, Vh, ctx);
  gemm_final_k<<<1024, 256, 0, stream>>>(ctx, W2, b2, x, out);
}